// Round 6
// baseline (100.409 us; speedup 1.0000x reference)
//
#include <hip/hip_runtime.h>

// PixelVectorExtractor: one transformer encoder layer over per-pixel 7x7
// windows in a 30x30 canvas (S=900, D=11). Structure exploited:
//  - only 49/900 rows nonzero; 851 zero rows share ONE output vector.
//  - zero-score keys: +851 to softmax denom, nothing to numerator.
// R5 post-mortem: block-phase version was bound by its own structure
// (11 phases x 9-wave barriers + per-phase LDS latency), not LDS throughput.
// v6: WAVE-SYNCHRONOUS. One 64-lane wave per pixel (TPB=64, grid=256 ->
// 1 block/CU). Lane r owns row r fully in registers (seq, q, num, x1, h[64],
// y); LDS used only for (a) staged weights, (b) K/V tables, (c) final rows
// for the epilogue -- all read as same-address broadcasts (conflict-free).
// LayerNorm = in-register per-lane. 3 single-wave barriers total.

#define D 11
#define ROWP 12
#define NW 49
#define NR 50
#define SEQ 900
#define FFD 64
#define CIN 10
#define NB 256
#define TPB 64

// dot of a 12-float LDS row (16B-aligned, pads=0) with 3 float4 registers
__device__ __forceinline__ float dotb(const float* row,
                                      const float4 a0, const float4 a1,
                                      const float4 a2) {
    const float4* r4 = (const float4*)row;
    const float4 x = r4[0], y = r4[1], z = r4[2];
    return a0.x * x.x + a0.y * x.y + a0.z * x.z + a0.w * x.w
         + a1.x * y.x + a1.y * y.y + a1.z * y.z + a1.w * y.w
         + a2.x * z.x + a2.y * z.y + a2.z * z.z + a2.w * z.w;
}

__global__ __launch_bounds__(TPB) void pve_kernel(
    const float* __restrict__ gx,     // [10,16,16]
    const float* __restrict__ gWqkv,  // [33,11]
    const float* __restrict__ gWo,    // [11,11]
    const float* __restrict__ gW1,    // [64,11]
    const float* __restrict__ gW2,    // [11,64]
    const float* __restrict__ gln1,   // [11]
    const float* __restrict__ gln2,   // [11]
    float* __restrict__ out)          // [256,10,900]
{
    __shared__ __align__(16) float sQ[33 * ROWP];   // Wqkv rows, padded, pads=0
    __shared__ __align__(16) float sWo[D * ROWP];
    __shared__ __align__(16) float sW1[FFD * ROWP];
    __shared__ __align__(16) float sW2[D * FFD];    // rows of 64
    __shared__ __align__(16) float sln1[ROWP], sln2[ROWP];
    __shared__ __align__(16) float sK[NW][ROWP];    // pads=0
    __shared__ __align__(16) float sV[NW][ROWP];
    __shared__ __align__(16) float sR[NR][ROWP];    // sR[49] = zero-row output

    const int tid = threadIdx.x;      // lane; r = tid (rows 0..48, 49 = zero)
    const int b = blockIdx.x;
    const int h = b >> 4;
    const int w = b & 15;
    const int r = tid;

    // ---- stage weights into LDS (pads zeroed) ----
    for (int i = tid; i < 33 * ROWP; i += TPB) {
        const int rr = i / ROWP, cc = i - rr * ROWP;
        sQ[i] = (cc < D) ? gWqkv[rr * D + cc] : 0.f;
    }
    for (int i = tid; i < D * ROWP; i += TPB) {
        const int rr = i / ROWP, cc = i - rr * ROWP;
        sWo[i] = (cc < D) ? gWo[rr * D + cc] : 0.f;
    }
    for (int i = tid; i < FFD * ROWP; i += TPB) {
        const int rr = i / ROWP, cc = i - rr * ROWP;
        sW1[i] = (cc < D) ? gW1[rr * D + cc] : 0.f;
    }
    for (int i = tid; i < D * FFD; i += TPB) sW2[i] = gW2[i];
    if (tid < ROWP) {
        sln1[tid] = (tid < D) ? gln1[tid] : 0.f;
        sln2[tid] = (tid < D) ? gln2[tid] : 0.f;
    }

    // ---- this lane's input row (registers) ----
    float sq[ROWP];
    #pragma unroll
    for (int d = 0; d < ROWP; ++d) sq[d] = 0.f;
    if (r < NW) {
        const int i = r / 7, j = r - (r / 7) * 7;
        const int y = h + i, xx = w + j;
        const bool inter = (y >= 3) && (y < 19) && (xx >= 3) && (xx < 19);
        const int base = inter ? ((y - 3) * 16 + (xx - 3)) : 0;
        #pragma unroll
        for (int d = 0; d < CIN; ++d) sq[d] = inter ? gx[d * 256 + base] : 0.f;
        sq[CIN] = inter ? 0.f : 1.f;         // mask channel
    }
    const float4 a0 = make_float4(sq[0], sq[1], sq[2],  sq[3]);
    const float4 a1 = make_float4(sq[4], sq[5], sq[6],  sq[7]);
    const float4 a2 = make_float4(sq[8], sq[9], sq[10], 0.f);

    __syncthreads();   // weights visible

    // ---- qkv projection (weights = LDS broadcasts) ----
    float qq[D], kk[D], vv[D];
    #pragma unroll
    for (int d = 0; d < D; ++d) {
        qq[d] = dotb(&sQ[d * ROWP],            a0, a1, a2);
        kk[d] = dotb(&sQ[(D + d) * ROWP],      a0, a1, a2);
        vv[d] = dotb(&sQ[(2 * D + d) * ROWP],  a0, a1, a2);
    }
    if (r < NW) {
        float4* K4 = (float4*)&sK[r][0];
        float4* V4 = (float4*)&sV[r][0];
        K4[0] = make_float4(kk[0], kk[1], kk[2],  kk[3]);
        K4[1] = make_float4(kk[4], kk[5], kk[6],  kk[7]);
        K4[2] = make_float4(kk[8], kk[9], kk[10], 0.f);
        V4[0] = make_float4(vv[0], vv[1], vv[2],  vv[3]);
        V4[1] = make_float4(vv[4], vv[5], vv[6],  vv[7]);
        V4[2] = make_float4(vv[8], vv[9], vv[10], 0.f);
    }
    const float4 q0 = make_float4(qq[0], qq[1], qq[2],  qq[3]);
    const float4 q1 = make_float4(qq[4], qq[5], qq[6],  qq[7]);
    const float4 q2 = make_float4(qq[8], qq[9], qq[10], 0.f);

    __syncthreads();   // K,V visible

    // ---- attention: 49 keys, all LDS reads are broadcasts ----
    const float scale = 0.30151134457776363f;   // 1/sqrt(11)
    float4 n0 = make_float4(0.f, 0.f, 0.f, 0.f);
    float4 n1 = n0, n2 = n0;
    float den = 851.0f;                          // 851 zero-score keys
    #pragma unroll 7
    for (int t = 0; t < NW; ++t) {
        const float s = dotb(&sK[t][0], q0, q1, q2) * scale;
        const float e = __expf(s);
        den += e;
        const float4* Vt = (const float4*)&sV[t][0];
        const float4 u = Vt[0], p = Vt[1], m2 = Vt[2];
        n0.x += e * u.x;  n0.y += e * u.y;  n0.z += e * u.z;  n0.w += e * u.w;
        n1.x += e * p.x;  n1.y += e * p.y;  n1.z += e * p.z;  n1.w += e * p.w;
        n2.x += e * m2.x; n2.y += e * m2.y; n2.z += e * m2.z;
    }
    const float inv = 1.0f / den;

    // ---- out-proj + residual + LN1 (in-register) ----
    float x1[D];
    #pragma unroll
    for (int d = 0; d < D; ++d)
        x1[d] = sq[d] + dotb(&sWo[d * ROWP], n0, n1, n2) * inv;
    float mean = 0.f;
    #pragma unroll
    for (int d = 0; d < D; ++d) mean += x1[d];
    mean *= (1.0f / 11.0f);
    float var = 0.f;
    #pragma unroll
    for (int d = 0; d < D; ++d) { const float t = x1[d] - mean; var += t * t; }
    var *= (1.0f / 11.0f);
    float rinv = rsqrtf(var + 1e-5f);
    float xn[D];
    #pragma unroll
    for (int d = 0; d < D; ++d) xn[d] = (x1[d] - mean) * rinv * sln1[d];
    const float4 b0 = make_float4(xn[0], xn[1], xn[2],  xn[3]);
    const float4 b1 = make_float4(xn[4], xn[5], xn[6],  xn[7]);
    const float4 b2 = make_float4(xn[8], xn[9], xn[10], 0.f);

    // ---- FF: 11 -> 64 relu -> 11, hidden in registers ----
    float hbuf[FFD];
    #pragma unroll 8
    for (int f = 0; f < FFD; ++f)
        hbuf[f] = fmaxf(dotb(&sW1[f * ROWP], b0, b1, b2), 0.f);
    float yv[D];
    #pragma unroll
    for (int d = 0; d < D; ++d) {
        const float4* w4 = (const float4*)&sW2[d * FFD];
        float acc = 0.f;
        #pragma unroll
        for (int i = 0; i < 16; ++i) {
            const float4 ww = w4[i];
            acc += hbuf[4 * i]     * ww.x + hbuf[4 * i + 1] * ww.y
                 + hbuf[4 * i + 2] * ww.z + hbuf[4 * i + 3] * ww.w;
        }
        yv[d] = xn[d] + acc;
    }

    // ---- LN2 (in-register), write final row ----
    mean = 0.f;
    #pragma unroll
    for (int d = 0; d < D; ++d) mean += yv[d];
    mean *= (1.0f / 11.0f);
    var = 0.f;
    #pragma unroll
    for (int d = 0; d < D; ++d) { const float t = yv[d] - mean; var += t * t; }
    var *= (1.0f / 11.0f);
    rinv = rsqrtf(var + 1e-5f);
    if (r < NR) {
        float rr[ROWP];
        #pragma unroll
        for (int d = 0; d < D; ++d) rr[d] = (yv[d] - mean) * rinv * sln2[d];
        rr[D] = 0.f;
        float4* R4 = (float4*)&sR[r][0];
        R4[0] = make_float4(rr[0], rr[1], rr[2],  rr[3]);
        R4[1] = make_float4(rr[4], rr[5], rr[6],  rr[7]);
        R4[2] = make_float4(rr[8], rr[9], rr[10], rr[11]);
    }
    __syncthreads();   // R visible

    // ---- epilogue: out[b,c,s], 2250 float4 by 64 lanes ----
    float4* ob4 = (float4*)(out + b * (CIN * SEQ));
    #pragma unroll
    for (int k = 0; k < 36; ++k) {
        const int qi = tid + k * TPB;
        if (qi < 2250) {
            const int c  = qi / 225;             // 225 float4 per channel
            const int s0 = (qi - c * 225) * 4;
            const float zv = sR[NW][c];
            float4 v4;
            float* pv = (float*)&v4;
            #pragma unroll
            for (int u = 0; u < 4; ++u) {
                const int s = s0 + u;
                const int i = s / 30;
                const int j = s - i * 30;
                pv[u] = (i < 7 && j < 7) ? sR[i * 7 + j][c] : zv;
            }
            ob4[qi] = v4;
        }
    }
}

extern "C" void kernel_launch(void* const* d_in, const int* in_sizes, int n_in,
                              void* d_out, int out_size, void* d_ws, size_t ws_size,
                              hipStream_t stream) {
    (void)in_sizes; (void)n_in; (void)out_size; (void)d_ws; (void)ws_size;
    const float* x    = (const float*)d_in[0];
    const float* Wqkv = (const float*)d_in[1];
    const float* Wo   = (const float*)d_in[2];
    const float* W1   = (const float*)d_in[3];
    const float* W2   = (const float*)d_in[4];
    const float* ln1  = (const float*)d_in[5];
    const float* ln2  = (const float*)d_in[6];
    pve_kernel<<<NB, TPB, 0, stream>>>(x, Wqkv, Wo, W1, W2, ln1, ln2,
                                       (float*)d_out);
}

// Round 7
// 81.289 us; speedup vs baseline: 1.2352x; 1.2352x over previous
//
#include <hip/hip_runtime.h>

// PixelVectorExtractor: one transformer encoder layer over per-pixel 7x7
// windows in a 30x30 canvas (S=900, D=11).
//  - only 49/900 rows nonzero; 851 zero rows share ONE output vector.
//  - zero-score keys: +851 to softmax denom, nothing to numerator.
// R6 post-mortem: 1-wave/CU wave-sync version = 37us, VALUBusy 0.07% --
// wall-clock equals ONE wave's serial latency chain; co-resident waves
// (R5's 9-wave phase kernel, 17us) are what actually hide the latency.
// v7: A/B split. Kernel A = R5's phase structure (proven best) MINUS the
// epilogue: phase 8 stores the 256x10x50 row table T[b][c][row] straight to
// d_ws (no sR, no final barriers, no conflicted LDS epilogue). Kernel B =
// wide broadcast-write (2250 blocks x 256 thr, one float4/thread) reading T
// from L2 and writing the 9.2 MB output at near-bandwidth.

#define D 11
#define ROWP 12      // padded row length (3 x float4), pads = 0
#define NW 49
#define NWP 52       // padded score-row length (13 x float4), pads = 0
#define NR 50
#define SEQ 900
#define FFD 64
#define CIN 10
#define NB 256
#define TPB 576
#define NRD (NR * D)  // 550
#define TROW 52       // T row stride (floats) per (b,c)

__device__ __forceinline__ float dot12(const float4* a, const float4* b) {
    float4 s = make_float4(0.f, 0.f, 0.f, 0.f);
    #pragma unroll
    for (int i = 0; i < 3; ++i) {
        float4 x = a[i], y = b[i];
        s.x += x.x * y.x; s.y += x.y * y.y; s.z += x.z * y.z; s.w += x.w * y.w;
    }
    return s.x + s.y + s.z + s.w;
}

__global__ __launch_bounds__(TPB) void pve_rows(
    const float* __restrict__ gx,     // [10,16,16]
    const float* __restrict__ gWqkv,  // [33,11]
    const float* __restrict__ gWo,    // [11,11]
    const float* __restrict__ gW1,    // [64,11]
    const float* __restrict__ gW2,    // [11,64]
    const float* __restrict__ gln1,   // [11]
    const float* __restrict__ gln2,   // [11]
    float* __restrict__ T)            // [256,10,52] row table
{
    __shared__ __align__(16) float sQ[33 * ROWP];    // Wqkv rows, padded
    __shared__ __align__(16) float sWo[D * ROWP];
    __shared__ __align__(16) float sW1[FFD * ROWP];
    __shared__ __align__(16) float sW2[D * FFD];     // rows of 64
    __shared__ float sln1[D], sln2[D];
    __shared__ __align__(16) float sSeq[NR][ROWP];
    __shared__ __align__(16) float sK[NW][ROWP];
    __shared__ __align__(16) float sVt[D][NWP];      // V transposed, [d][t]
    __shared__ __align__(16) float sQr[NR][ROWP];
    __shared__ __align__(16) float sE[NR][NWP];      // exp(scores), pads = 0
    __shared__ __align__(16) float sNum[NR][ROWP];
    __shared__ float sDen[NR];
    __shared__ __align__(16) float sX1[NR][ROWP];
    __shared__ __align__(16) float sX1n[NR][ROWP];
    __shared__ __align__(16) float sH[NR][FFD];
    __shared__ __align__(16) float sY[NR][ROWP];

    const int tid = threadIdx.x;
    const int b = blockIdx.x;
    const int h = b >> 4;
    const int w = b & 15;

    const int rd = tid;               // (r,d), valid when < 550
    const int r = rd / D;
    const int d = rd - r * D;

    // ---- phase 0: stage weights (zero-padded rows) + build seq rows ----
    // all staging loops are <=2 iterations at TPB=576
    for (int i = tid; i < 33 * ROWP; i += TPB) {
        const int rr = i / ROWP, cc = i - rr * ROWP;
        sQ[i] = (cc < D) ? gWqkv[rr * D + cc] : 0.f;
    }
    for (int i = tid; i < D * ROWP; i += TPB) {
        const int rr = i / ROWP, cc = i - rr * ROWP;
        sWo[i] = (cc < D) ? gWo[rr * D + cc] : 0.f;
    }
    for (int i = tid; i < FFD * ROWP; i += TPB) {
        const int rr = i / ROWP, cc = i - rr * ROWP;
        sW1[i] = (cc < D) ? gW1[rr * D + cc] : 0.f;
    }
    for (int i = tid; i < D * FFD; i += TPB) sW2[i] = gW2[i];
    if (tid < D) { sln1[tid] = gln1[tid]; sln2[tid] = gln2[tid]; }

    if (rd < NRD) {
        float val = 0.0f;
        if (r < NW) {
            const int i = r / 7, j = r - (r / 7) * 7;
            const int y = h + i, xx = w + j;
            const bool inter = (y >= 3) && (y < 19) && (xx >= 3) && (xx < 19);
            const int base = inter ? ((y - 3) * 16 + (xx - 3)) : 0;
            if (d < CIN) val = inter ? gx[d * 256 + base] : 0.0f;
            else         val = inter ? 0.0f : 1.0f;     // mask channel
        }
        sSeq[r][d] = val;
        if (d == CIN) sSeq[r][D] = 0.f;                 // row pad
    }
    __syncthreads();

    // ---- phase 1: qkv projection, thread=(r,d); V written transposed ----
    if (rd < NRD) {
        const float4* sv = (const float4*)&sSeq[r][0];
        const float aq = dot12(sv, (const float4*)&sQ[d * ROWP]);
        const float ak = dot12(sv, (const float4*)&sQ[(D + d) * ROWP]);
        const float av = dot12(sv, (const float4*)&sQ[(2 * D + d) * ROWP]);
        sQr[r][d] = aq;
        if (d == CIN) sQr[r][D] = 0.f;
        if (r < NW) { sK[r][d] = ak; sVt[d][r] = av;
                      if (d == CIN) sK[r][D] = 0.f; }
        else { sVt[d][NW] = 0.f; sVt[d][NW + 1] = 0.f; sVt[d][NW + 2] = 0.f; }
    }
    __syncthreads();

    // ---- phase 2: scores + exp over padded 50x52 grid ----
    {
        const float scale = 0.30151134457776363f;   // 1/sqrt(11)
        #pragma unroll
        for (int k = 0; k < 5; ++k) {
            const int idx = tid + k * TPB;
            if (idx < NR * NWP) {
                const int rr = idx / NWP;
                const int tt = idx - rr * NWP;
                float e = 0.f;
                if (tt < NW) {
                    const float s = dot12((const float4*)&sQr[rr][0],
                                          (const float4*)&sK[tt][0]);
                    e = __expf(s * scale);
                }
                sE[rr][tt] = e;                     // pads get exactly 0
            }
        }
    }
    __syncthreads();

    // ---- phase 3: softmax numerator (and denom on d==0 lanes) ----
    if (rd < NRD) {
        const float4* ev = (const float4*)&sE[r][0];
        const float4* vv = (const float4*)&sVt[d][0];
        float4 an = make_float4(0.f, 0.f, 0.f, 0.f);
        float4 ad = make_float4(0.f, 0.f, 0.f, 0.f);
        #pragma unroll
        for (int i = 0; i < 13; ++i) {
            const float4 e = ev[i], v = vv[i];
            an.x += e.x * v.x; an.y += e.y * v.y;
            an.z += e.z * v.z; an.w += e.w * v.w;
            ad.x += e.x; ad.y += e.y; ad.z += e.z; ad.w += e.w;
        }
        sNum[r][d] = an.x + an.y + an.z + an.w;
        if (d == CIN) sNum[r][D] = 0.f;
        if (d == 0) sDen[r] = 851.0f + ad.x + ad.y + ad.z + ad.w;
    }
    __syncthreads();

    // ---- phase 4: out-proj + residual ----
    if (rd < NRD) {
        const float acc = dot12((const float4*)&sNum[r][0],
                                (const float4*)&sWo[d * ROWP]);
        sX1[r][d] = sSeq[r][d] + acc / sDen[r];
        if (d == CIN) sX1[r][D] = 0.f;
    }
    __syncthreads();

    // ---- phase 5: LN1 (pads are 0; raw-moment form) ----
    if (rd < NRD) {
        const float4* xv = (const float4*)&sX1[r][0];
        float4 s4 = make_float4(0.f, 0.f, 0.f, 0.f);
        float4 q4 = make_float4(0.f, 0.f, 0.f, 0.f);
        #pragma unroll
        for (int i = 0; i < 3; ++i) {
            const float4 x = xv[i];
            s4.x += x.x; s4.y += x.y; s4.z += x.z; s4.w += x.w;
            q4.x += x.x * x.x; q4.y += x.y * x.y;
            q4.z += x.z * x.z; q4.w += x.w * x.w;
        }
        const float sum = s4.x + s4.y + s4.z + s4.w;
        const float sq  = q4.x + q4.y + q4.z + q4.w;
        const float m   = sum * (1.0f / 11.0f);
        const float var = sq * (1.0f / 11.0f) - m * m;
        sX1n[r][d] = (sX1[r][d] - m) * rsqrtf(var + 1e-5f) * sln1[d];
        if (d == CIN) sX1n[r][D] = 0.f;
    }
    __syncthreads();

    // ---- phase 6: FF hidden, 50x64 over 576 threads ----
    #pragma unroll
    for (int k = 0; k < 6; ++k) {
        const int idx = tid + k * TPB;
        if (idx < NR * FFD) {
            const int rr = idx >> 6;
            const int ff = idx & 63;
            const float acc = dot12((const float4*)&sX1n[rr][0],
                                    (const float4*)&sW1[ff * ROWP]);
            sH[rr][ff] = fmaxf(acc, 0.0f);
        }
    }
    __syncthreads();

    // ---- phase 7: FF out + residual (contiguous over f) ----
    if (rd < NRD) {
        const float4* hv = (const float4*)&sH[r][0];
        const float4* wv = (const float4*)&sW2[d * FFD];
        float4 a4 = make_float4(0.f, 0.f, 0.f, 0.f);
        #pragma unroll
        for (int i = 0; i < 16; ++i) {
            const float4 hh = hv[i], ww = wv[i];
            a4.x += hh.x * ww.x; a4.y += hh.y * ww.y;
            a4.z += hh.z * ww.z; a4.w += hh.w * ww.w;
        }
        sY[r][d] = sX1n[r][d] + a4.x + a4.y + a4.z + a4.w;
        if (d == CIN) sY[r][D] = 0.f;
    }
    __syncthreads();

    // ---- phase 8: LN2 + direct store of row table to global ----
    if (rd < NRD) {
        const float4* yv = (const float4*)&sY[r][0];
        float4 s4 = make_float4(0.f, 0.f, 0.f, 0.f);
        float4 q4 = make_float4(0.f, 0.f, 0.f, 0.f);
        #pragma unroll
        for (int i = 0; i < 3; ++i) {
            const float4 y = yv[i];
            s4.x += y.x; s4.y += y.y; s4.z += y.z; s4.w += y.w;
            q4.x += y.x * y.x; q4.y += y.y * y.y;
            q4.z += y.z * y.z; q4.w += y.w * y.w;
        }
        const float sum = s4.x + s4.y + s4.z + s4.w;
        const float sq  = q4.x + q4.y + q4.z + q4.w;
        const float m   = sum * (1.0f / 11.0f);
        const float var = sq * (1.0f / 11.0f) - m * m;
        const float val = (sY[r][d] - m) * rsqrtf(var + 1e-5f) * sln2[d];
        if (d < CIN)                       // mask channel (d==10) is dropped
            T[(b * CIN + d) * TROW + r] = val;
    }
}

// Kernel B: pure broadcast write. One float4 per thread; 2250 blocks x 256.
__global__ __launch_bounds__(256) void pve_write(
    const float* __restrict__ T,      // [256,10,52]
    float4* __restrict__ out4)        // [256*10*900/4]
{
    const int flat = blockIdx.x * 256 + threadIdx.x;   // < 576000
    const int b   = flat / 2250;
    const int rem = flat - b * 2250;
    const int c   = rem / 225;                         // 225 float4 / channel
    const int s0  = (rem - c * 225) * 4;
    const float* tb = T + (b * CIN + c) * TROW;
    float4 v4;
    float* pv = (float*)&v4;
    #pragma unroll
    for (int u = 0; u < 4; ++u) {
        const int s = s0 + u;
        const int i = s / 30;
        const int j = s - i * 30;
        const int row = (i < 7 && j < 7) ? (i * 7 + j) : NW;   // 49 = zero row
        pv[u] = tb[row];
    }
    out4[flat] = v4;
}

extern "C" void kernel_launch(void* const* d_in, const int* in_sizes, int n_in,
                              void* d_out, int out_size, void* d_ws, size_t ws_size,
                              hipStream_t stream) {
    (void)in_sizes; (void)n_in; (void)out_size; (void)ws_size;
    const float* x    = (const float*)d_in[0];
    const float* Wqkv = (const float*)d_in[1];
    const float* Wo   = (const float*)d_in[2];
    const float* W1   = (const float*)d_in[3];
    const float* W2   = (const float*)d_in[4];
    const float* ln1  = (const float*)d_in[5];
    const float* ln2  = (const float*)d_in[6];
    float* T = (float*)d_ws;          // 256*10*52 floats = 532 KB
    pve_rows<<<NB, TPB, 0, stream>>>(x, Wqkv, Wo, W1, W2, ln1, ln2, T);
    pve_write<<<576000 / 256, 256, 0, stream>>>(T, (float4*)d_out);
}